// Round 1
// baseline (27.486 us; speedup 1.0000x reference)
//
#include <hip/hip_runtime.h>

// Reference collapses: softmax over axis of size 1 == 1.0, so
// out[e] = sum_f h[edge_src[e], f].  W/b/leaky_relu/edge_dst are dead.

#define FDIM 128

// One 64-lane wave per row; each lane loads float2 (2 elems), tree-reduce.
__global__ void rowsum_kernel(const float* __restrict__ h,
                              float* __restrict__ rowsum, int N) {
    const int gid  = blockIdx.x * blockDim.x + threadIdx.x;
    const int row  = gid >> 6;          // wave index = row
    const int lane = threadIdx.x & 63;
    if (row >= N) return;
    const float2 v =
        *reinterpret_cast<const float2*>(h + (size_t)row * FDIM + lane * 2);
    float s = v.x + v.y;
#pragma unroll
    for (int off = 32; off > 0; off >>= 1)
        s += __shfl_down(s, off, 64);
    if (lane == 0) rowsum[row] = s;
}

__global__ void gather_kernel(const int* __restrict__ esrc,
                              const float* __restrict__ rowsum,
                              float* __restrict__ out, int E) {
    const int e = blockIdx.x * blockDim.x + threadIdx.x;
    if (e < E) out[e] = rowsum[esrc[e]];
}

extern "C" void kernel_launch(void* const* d_in, const int* in_sizes, int n_in,
                              void* d_out, int out_size, void* d_ws, size_t ws_size,
                              hipStream_t stream) {
    const float* h    = (const float*)d_in[0];   // [N, 128]
    const int*   esrc = (const int*)d_in[3];     // [E]
    float* out    = (float*)d_out;               // [E]
    float* rowsum = (float*)d_ws;                // [N] scratch

    const int N = in_sizes[0] / FDIM;
    const int E = in_sizes[3];

    // Kernel 1: one wave per row -> 64*N threads.
    {
        const int block = 256;
        const int rows_per_block = block / 64;
        const int grid = (N + rows_per_block - 1) / rows_per_block;
        rowsum_kernel<<<grid, block, 0, stream>>>(h, rowsum, N);
    }
    // Kernel 2: one thread per edge.
    {
        const int block = 256;
        const int grid = (E + block - 1) / block;
        gather_kernel<<<grid, block, 0, stream>>>(esrc, rowsum, out, E);
    }
}

// Round 2
// 24.329 us; speedup vs baseline: 1.1298x; 1.1298x over previous
//
#include <hip/hip_runtime.h>

// Reference collapses: softmax over axis of size 1 == 1.0, so
// out[e] = sum_f h[edge_src[e], f].  W/b/leaky_relu/edge_dst are dead.

#define FDIM 128

// One 64-lane wave handles TWO rows: each 32-lane half reads one row as
// float4 (16 B/lane -> 1 KiB contiguous per wave), then 5-step shfl_xor
// reduction within the half.
__global__ void rowsum_kernel(const float* __restrict__ h,
                              float* __restrict__ rowsum, int N) {
    const int gid  = blockIdx.x * blockDim.x + threadIdx.x;
    const int wave = gid >> 6;
    const int lane = threadIdx.x & 63;
    const int row  = wave * 2 + (lane >> 5);
    if (row >= N) return;
    const float4 v = *reinterpret_cast<const float4*>(
        h + (size_t)row * FDIM + (lane & 31) * 4);
    float s = (v.x + v.y) + (v.z + v.w);
#pragma unroll
    for (int off = 16; off > 0; off >>= 1)   // stays within the 32-lane half
        s += __shfl_xor(s, off, 64);
    if ((lane & 31) == 0) rowsum[row] = s;
}

// 4 edges per thread: int4 index load + float4 store (16 B/lane both sides);
// rowsum table (400 KB) is L2-resident.
__global__ void gather_kernel(const int* __restrict__ esrc,
                              const float* __restrict__ rowsum,
                              float* __restrict__ out, int E) {
    const int t = blockIdx.x * blockDim.x + threadIdx.x;
    const int e = t << 2;
    if (e + 3 < E) {
        const int4 idx = *reinterpret_cast<const int4*>(esrc + e);
        float4 o;
        o.x = rowsum[idx.x];
        o.y = rowsum[idx.y];
        o.z = rowsum[idx.z];
        o.w = rowsum[idx.w];
        *reinterpret_cast<float4*>(out + e) = o;
    } else if (e < E) {
        for (int i = e; i < E; ++i) out[i] = rowsum[esrc[i]];
    }
}

extern "C" void kernel_launch(void* const* d_in, const int* in_sizes, int n_in,
                              void* d_out, int out_size, void* d_ws, size_t ws_size,
                              hipStream_t stream) {
    const float* h    = (const float*)d_in[0];   // [N, 128]
    const int*   esrc = (const int*)d_in[3];     // [E]
    float* out    = (float*)d_out;               // [E]
    float* rowsum = (float*)d_ws;                // [N] scratch

    const int N = in_sizes[0] / FDIM;
    const int E = in_sizes[3];

    // Kernel 1: 2 rows per wave, 4 waves per block -> 8 rows/block.
    {
        const int block = 256;
        const int rows_per_block = 8;
        const int grid = (N + rows_per_block - 1) / rows_per_block;
        rowsum_kernel<<<grid, block, 0, stream>>>(h, rowsum, N);
    }
    // Kernel 2: 4 edges per thread.
    {
        const int block = 256;
        const int quads = (E + 3) / 4;
        const int grid = (quads + block - 1) / block;
        gather_kernel<<<grid, block, 0, stream>>>(esrc, rowsum, out, E);
    }
}

// Round 3
// 24.082 us; speedup vs baseline: 1.1414x; 1.0103x over previous
//
#include <hip/hip_runtime.h>

// Reference collapses: softmax over axis of size 1 == 1.0, so
// out[e] = sum_f h[edge_src[e], f].  W/b/leaky_relu/edge_dst are dead.
//
// Two-pass: (1) rowsum[n] = sum(h[n,:]) ; (2) out[e] = rowsum[esrc[e]].
// Both kernels are persistent grid-stride with hand-unrolled independent
// loads so each wave keeps 4 (rowsum) / 2 (gather) vmem ops in flight.

#define FDIM 128

// Wave layout: 2 rows per wave (each 32-lane half = one row, float4/lane).
// Grid-stride over row-pairs, unrolled x4 -> 4 independent 1KiB wave-loads
// in flight before the shuffle reduces.
__global__ __launch_bounds__(256) void rowsum_kernel(
    const float4* __restrict__ h4, float* __restrict__ rowsum,
    int Pm /* N/2 */, int P /* ceil(N/2) */, int N) {
    const int lane = threadIdx.x & 63;
    const int half = lane >> 5;       // which row of the pair
    const int l32  = lane & 31;
    const int wave = (blockIdx.x * 256 + threadIdx.x) >> 6;
    const int nw   = (gridDim.x * 256) >> 6;

    int i = wave;
    for (; i + 3 * nw < Pm; i += 4 * nw) {
        const int r0 = 2 * i + half;
        const int r1 = 2 * (i + nw) + half;
        const int r2 = 2 * (i + 2 * nw) + half;
        const int r3 = 2 * (i + 3 * nw) + half;
        const float4 v0 = h4[(size_t)r0 * 32 + l32];
        const float4 v1 = h4[(size_t)r1 * 32 + l32];
        const float4 v2 = h4[(size_t)r2 * 32 + l32];
        const float4 v3 = h4[(size_t)r3 * 32 + l32];
        float s0 = (v0.x + v0.y) + (v0.z + v0.w);
        float s1 = (v1.x + v1.y) + (v1.z + v1.w);
        float s2 = (v2.x + v2.y) + (v2.z + v2.w);
        float s3 = (v3.x + v3.y) + (v3.z + v3.w);
#pragma unroll
        for (int off = 16; off > 0; off >>= 1) {
            s0 += __shfl_xor(s0, off, 64);
            s1 += __shfl_xor(s1, off, 64);
            s2 += __shfl_xor(s2, off, 64);
            s3 += __shfl_xor(s3, off, 64);
        }
        if (l32 == 0) {
            rowsum[r0] = s0;
            rowsum[r1] = s1;
            rowsum[r2] = s2;
            rowsum[r3] = s3;
        }
    }
    for (; i < P; i += nw) {
        const int r = 2 * i + half;
        if (r < N) {
            const float4 v = h4[(size_t)r * 32 + l32];
            float s = (v.x + v.y) + (v.z + v.w);
#pragma unroll
            for (int off = 16; off > 0; off >>= 1) s += __shfl_xor(s, off, 64);
            if (l32 == 0) rowsum[r] = s;
        }
    }
}

// 2 independent quads per thread: 2x int4 loads + 8 L2-hit table reads +
// 2x float4 stores in flight.  rowsum table (400 KB) is L2-resident.
__global__ __launch_bounds__(256) void gather_kernel(
    const int* __restrict__ esrc, const float* __restrict__ rowsum,
    float* __restrict__ out, int Q /* E/4 */, int E) {
    const int t      = blockIdx.x * 256 + threadIdx.x;
    const int stride = gridDim.x * 256;

    int q0 = t, q1 = t + stride;
    for (; q1 < Q; q0 += 2 * stride, q1 += 2 * stride) {
        const int4 ia = *reinterpret_cast<const int4*>(esrc + q0 * 4);
        const int4 ib = *reinterpret_cast<const int4*>(esrc + q1 * 4);
        float4 oa, ob;
        oa.x = rowsum[ia.x]; oa.y = rowsum[ia.y];
        oa.z = rowsum[ia.z]; oa.w = rowsum[ia.w];
        ob.x = rowsum[ib.x]; ob.y = rowsum[ib.y];
        ob.z = rowsum[ib.z]; ob.w = rowsum[ib.w];
        *reinterpret_cast<float4*>(out + q0 * 4) = oa;
        *reinterpret_cast<float4*>(out + q1 * 4) = ob;
    }
    for (; q0 < Q; q0 += stride) {
        const int4 ia = *reinterpret_cast<const int4*>(esrc + q0 * 4);
        float4 oa;
        oa.x = rowsum[ia.x]; oa.y = rowsum[ia.y];
        oa.z = rowsum[ia.z]; oa.w = rowsum[ia.w];
        *reinterpret_cast<float4*>(out + q0 * 4) = oa;
    }
    // tail edges (E not multiple of 4)
    const int rem = Q * 4 + t;
    if (rem < E) out[rem] = rowsum[esrc[rem]];
}

extern "C" void kernel_launch(void* const* d_in, const int* in_sizes, int n_in,
                              void* d_out, int out_size, void* d_ws, size_t ws_size,
                              hipStream_t stream) {
    const float* h    = (const float*)d_in[0];   // [N, 128]
    const int*   esrc = (const int*)d_in[3];     // [E]
    float* out    = (float*)d_out;               // [E]
    float* rowsum = (float*)d_ws;                // [N] scratch

    const int N = in_sizes[0] / FDIM;
    const int E = in_sizes[3];

    {   // rowsum: persistent, ~4 blocks/CU
        const int grid = 1024;
        rowsum_kernel<<<grid, 256, 0, stream>>>(
            reinterpret_cast<const float4*>(h), rowsum, N / 2, (N + 1) / 2, N);
    }
    {   // gather: 2 quads per thread
        const int Q = E / 4;
        int grid = (Q + 2 * 256 - 1) / (2 * 256);
        if (grid < 1) grid = 1;
        gather_kernel<<<grid, 256, 0, stream>>>(esrc, rowsum, out, Q, E);
    }
}